// Round 3
// baseline (408.983 us; speedup 1.0000x reference)
//
#include <hip/hip_runtime.h>

#define TD 5
#define HD 80
#define WD 80
#define NPIX 32000           // 5*80*80
#define NPC 4000             // NPIX/8 pixel-chunks
#define KOFF 2204            // 5*21*21 - 1
#define CENTER_IDX 1102      // (10*21+10)*5 + 2
#define NB_PC 16             // 4096 threads cover 4000 chunks
#define NB_OFF 64
#define OFF_CHUNK 35         // ceil(2204/64); tail blocks partial/empty

typedef unsigned short u16t;
typedef unsigned int u32t;

__device__ __forceinline__ float bf2f(u32t u) {
    union { u32t i; float f; } v; v.i = u << 16; return v.f;
}

// ---------- dtype probe: flag=1 if tensors are bf16, 0 if float32 ----------
// bf16 data: every u32 word has an exponent-style byte at bits 15:8 AND 31:24.
// f32 data: bits 15:8 are random mantissa bits (P(in [0x38,0x40)) ~ 3%).
__global__ void dtype_probe(const u32t* __restrict__ t, int* __restrict__ flag)
{
    int lane = threadIdx.x;            // 64 threads
    u32t v = t[lane];
    int b1 = (v >> 8) & 0xFF;
    int b3 = (v >> 24) & 0xFF;
    bool bfp = (b1 >= 0x38 && b1 < 0x40) && (b3 >= 0x38 && b3 < 0x40);
    unsigned long long m = __ballot(bfp);
    if (lane == 0) *flag = (__popcll(m) >= 32) ? 1 : 0;
}

// ---------- per-thread accumulation, dtype-templated ----------
template<bool BF16>
__device__ __forceinline__ void accum_body(const void* __restrict__ wp,
                                           const void* __restrict__ tp,
                                           const void* __restrict__ op,
                                           int pc, int by,
                                           float& acc, float& facc)
{
    const int px0 = pc * 8;
    const int x0 = px0 % WD;
    const int rowc = px0 / WD;         // t*80 + y
    const int y = rowc % HD;
    const int t = rowc / HD;

    float c[8];                        // center values
    if (BF16) {
        uint4 cv = ((const uint4*)op)[pc];
        u32t u[4] = {cv.x, cv.y, cv.z, cv.w};
        #pragma unroll
        for (int q = 0; q < 4; ++q) {
            c[2*q]   = bf2f(u[q] & 0xffffu);
            c[2*q+1] = bf2f(u[q] >> 16);
        }
    } else {
        float4 a = ((const float4*)op)[pc*2];
        float4 b = ((const float4*)op)[pc*2+1];
        c[0]=a.x; c[1]=a.y; c[2]=a.z; c[3]=a.w;
        c[4]=b.x; c[5]=b.y; c[6]=b.z; c[7]=b.w;
    }

    if (by == 0) {                     // fidelity, computed once per pixel
        float tv[8];
        if (BF16) {
            uint4 q4 = ((const uint4*)tp)[pc];
            u32t u[4] = {q4.x, q4.y, q4.z, q4.w};
            #pragma unroll
            for (int q = 0; q < 4; ++q) {
                tv[2*q]   = bf2f(u[q] & 0xffffu);
                tv[2*q+1] = bf2f(u[q] >> 16);
            }
        } else {
            float4 a = ((const float4*)tp)[pc*2];
            float4 b = ((const float4*)tp)[pc*2+1];
            tv[0]=a.x; tv[1]=a.y; tv[2]=a.z; tv[3]=a.w;
            tv[4]=b.x; tv[5]=b.y; tv[6]=b.z; tv[7]=b.w;
        }
        #pragma unroll
        for (int q = 0; q < 8; ++q) {
            float d = c[q] - tv[q];
            facc += d * d;
        }
    }

    const float* of = (const float*)op;
    const u16t* ob = (const u16t*)op;

    const int off0 = by * OFF_CHUNK;
    const int off1 = min(off0 + OFF_CHUNK, KOFF);
    for (int off = off0; off < off1; ++off) {
        // offset enumeration: m = (i*21 + j)*5 + k, center skipped
        const int m  = off + (off >= CENTER_IDX ? 1 : 0);
        const int k  = m % 5;
        const int ij = m / 5;
        const int j  = ij % 21;
        const int i2 = ij / 21;
        int tz = t + k - 2;   tz = max(0, min(tz, TD - 1));
        int yz = y + i2 - 10; yz = max(0, min(yz, HD - 1));
        const int rowbase = (tz * HD + yz) * WD;
        const int xb = x0 + j - 10;

        float wv[8];
        if (BF16) {
            uint4 q4 = *(const uint4*)((const u16t*)wp + (size_t)off * NPIX + px0);
            u32t u[4] = {q4.x, q4.y, q4.z, q4.w};
            #pragma unroll
            for (int q = 0; q < 4; ++q) {
                wv[2*q]   = bf2f(u[q] & 0xffffu);
                wv[2*q+1] = bf2f(u[q] >> 16);
            }
        } else {
            const float* wf = (const float*)wp + (size_t)off * NPIX + px0;
            float4 a = *(const float4*)wf;
            float4 b = *(const float4*)(wf + 4);
            wv[0]=a.x; wv[1]=a.y; wv[2]=a.z; wv[3]=a.w;
            wv[4]=b.x; wv[5]=b.y; wv[6]=b.z; wv[7]=b.w;
        }

        #pragma unroll
        for (int q = 0; q < 8; ++q) {
            int xn = xb + q; xn = max(0, min(xn, WD - 1));   // replicate pad
            float nb = BF16 ? bf2f((u32t)ob[rowbase + xn]) : of[rowbase + xn];
            float d = c[q] - nb;
            acc = fmaf(wv[q] * d, d, acc);
        }
    }
}

// Grid: x = pixel-chunk block (16), y = offset block (64). Block = 256 threads.
__global__ __launch_bounds__(256) void bilateral_main(
    const void* __restrict__ w, const void* __restrict__ tgt,
    const void* __restrict__ outp, float* __restrict__ ws,
    const int* __restrict__ flag)
{
    __shared__ float red_s[4];
    __shared__ float red_f[4];

    const int tid = threadIdx.x;
    const int pc = blockIdx.x * 256 + tid;
    const int f = *flag;               // wave-uniform
    float acc = 0.f, facc = 0.f;

    if (pc < NPC) {
        if (f) accum_body<true >(w, tgt, outp, pc, blockIdx.y, acc, facc);
        else   accum_body<false>(w, tgt, outp, pc, blockIdx.y, acc, facc);
    }

    #pragma unroll
    for (int s = 32; s > 0; s >>= 1) {
        acc  += __shfl_down(acc, s, 64);
        facc += __shfl_down(facc, s, 64);
    }
    const int wid = tid >> 6, lane = tid & 63;
    if (lane == 0) { red_s[wid] = acc; red_f[wid] = facc; }
    __syncthreads();
    if (tid == 0) {
        atomicAdd(&ws[0], red_s[0] + red_s[1] + red_s[2] + red_s[3]);
        if (blockIdx.y == 0)
            atomicAdd(&ws[1], red_f[0] + red_f[1] + red_f[2] + red_f[3]);
    }
}

__global__ void bilateral_final(const float* __restrict__ ws,
                                const int* __restrict__ flag,
                                void* __restrict__ out)
{
    if (threadIdx.x == 0) {
        float res = (128.0f / (float)KOFF) * ws[0] + ws[1] / (float)NPIX;
        if (*flag) {                   // bf16 output, RNE
            u32t u = __float_as_uint(res);
            u32t lsb = (u >> 16) & 1u;
            u = (u + 0x7fffu + lsb) >> 16;
            ((u16t*)out)[0] = (u16t)u;
        } else {                       // f32 output
            ((float*)out)[0] = res;
        }
    }
}

extern "C" void kernel_launch(void* const* d_in, const int* in_sizes, int n_in,
                              void* d_out, int out_size, void* d_ws, size_t ws_size,
                              hipStream_t stream) {
    const void* w    = d_in[0];
    const void* tgt  = d_in[1];
    const void* outp = d_in[2];
    float* ws = (float*)d_ws;          // ws[0]=smooth, ws[1]=fidelity, ws[2]=flag
    int* flag = (int*)(ws + 2);

    hipMemsetAsync(d_ws, 0, 3 * sizeof(float), stream);
    dtype_probe<<<1, 64, 0, stream>>>((const u32t*)tgt, flag);
    dim3 grid(NB_PC, NB_OFF);
    bilateral_main<<<grid, 256, 0, stream>>>(w, tgt, outp, ws, flag);
    bilateral_final<<<1, 64, 0, stream>>>(ws, flag, d_out);
}

// Round 12
// 394.258 us; speedup vs baseline: 1.0373x; 1.0373x over previous
//
#include <hip/hip_runtime.h>

#define TD 5
#define HD 80
#define WD 80
#define NPIX 32000           // 5*80*80
#define KOFF 2204            // 5*21*21 - 1
#define CENTER_IDX 1102      // (10*21+10)*5 + 2
#define PX_PER_LANE 4
#define NB_PC 32             // ceil(32000 / (256*4)) = 31.25 -> 32
#define NB_OFF 64
#define OFF_CHUNK 35         // 64*35 = 2240 >= 2204

typedef unsigned short u16t;
typedef unsigned int u32t;
typedef float f32x4 __attribute__((ext_vector_type(4)));   // clang-native vec, ok for nontemporal builtin

__device__ __forceinline__ float bf2f(u32t u) {
    union { u32t i; float f; } v; v.i = u << 16; return v.f;
}

// ---------- dtype probe: flag=1 if tensors are bf16, 0 if float32 ----------
__global__ void dtype_probe(const u32t* __restrict__ t, int* __restrict__ flag)
{
    int lane = threadIdx.x;            // 64 threads
    u32t v = t[lane];
    int b1 = (v >> 8) & 0xFF;
    int b3 = (v >> 24) & 0xFF;
    bool bfp = (b1 >= 0x38 && b1 < 0x40) && (b3 >= 0x38 && b3 < 0x40);
    unsigned long long m = __ballot(bfp);
    if (lane == 0) *flag = (__popcll(m) >= 32) ? 1 : 0;
}

// ---------- f32 path: 4 consecutive pixels per lane ----------
// w load: one coalesced dwordx4 per lane per offset (1024B/wave contiguous).
// neighbor loads: scalar f32, lane stride 16B, lines fully reused over q=0..3.
__device__ __forceinline__ void accum_f32(const float* __restrict__ wf,
                                          const float* __restrict__ tf,
                                          const float* __restrict__ of,
                                          int px0, int by,
                                          float& acc, float& facc)
{
    const int x0 = px0 % WD;           // 4-aligned, chunk never crosses a row
    const int rowc = px0 / WD;         // t*80 + y
    const int y = rowc % HD;
    const int t = rowc / HD;

    const float4 c = *(const float4*)(of + px0);

    if (by == 0) {                     // fidelity, once per pixel
        float4 tv = *(const float4*)(tf + px0);
        float d0 = c.x - tv.x, d1 = c.y - tv.y, d2 = c.z - tv.z, d3 = c.w - tv.w;
        facc += d0*d0 + d1*d1 + d2*d2 + d3*d3;
    }

    const int off0 = by * OFF_CHUNK;
    const int off1 = min(off0 + OFF_CHUNK, KOFF);
    for (int off = off0; off < off1; ++off) {
        // offset enumeration: m = (i*21 + j)*5 + k, center skipped
        const int m  = off + (off >= CENTER_IDX ? 1 : 0);
        const int k  = m % 5;
        const int ij = m / 5;
        const int j  = ij % 21;
        const int i2 = ij / 21;
        int tz = t + k - 2;   tz = max(0, min(tz, TD - 1));
        int yz = y + i2 - 10; yz = max(0, min(yz, HD - 1));
        const int rowbase = (tz * HD + yz) * WD;
        const int xb = x0 + j - 10;

        const f32x4 wv = __builtin_nontemporal_load(
            (const f32x4*)(wf + (size_t)off * NPIX + px0));

        int x;
        float nb, d;
        x = max(0, min(xb,     WD - 1)); nb = of[rowbase + x]; d = c.x - nb; acc = fmaf(wv[0] * d, d, acc);
        x = max(0, min(xb + 1, WD - 1)); nb = of[rowbase + x]; d = c.y - nb; acc = fmaf(wv[1] * d, d, acc);
        x = max(0, min(xb + 2, WD - 1)); nb = of[rowbase + x]; d = c.z - nb; acc = fmaf(wv[2] * d, d, acc);
        x = max(0, min(xb + 3, WD - 1)); nb = of[rowbase + x]; d = c.w - nb; acc = fmaf(wv[3] * d, d, acc);
    }
}

// ---------- bf16 fallback path (same geometry, u16 loads) ----------
__device__ __forceinline__ void accum_bf16(const u16t* __restrict__ wb,
                                           const u16t* __restrict__ tb,
                                           const u16t* __restrict__ ob,
                                           int px0, int by,
                                           float& acc, float& facc)
{
    const int x0 = px0 % WD;
    const int rowc = px0 / WD;
    const int y = rowc % HD;
    const int t = rowc / HD;

    float c[4];
    {
        uint2 cv = *(const uint2*)(ob + px0);
        c[0] = bf2f(cv.x & 0xffffu); c[1] = bf2f(cv.x >> 16);
        c[2] = bf2f(cv.y & 0xffffu); c[3] = bf2f(cv.y >> 16);
    }
    if (by == 0) {
        uint2 tv = *(const uint2*)(tb + px0);
        float t0 = bf2f(tv.x & 0xffffu), t1 = bf2f(tv.x >> 16);
        float t2 = bf2f(tv.y & 0xffffu), t3 = bf2f(tv.y >> 16);
        float d0 = c[0]-t0, d1 = c[1]-t1, d2 = c[2]-t2, d3 = c[3]-t3;
        facc += d0*d0 + d1*d1 + d2*d2 + d3*d3;
    }

    const int off0 = by * OFF_CHUNK;
    const int off1 = min(off0 + OFF_CHUNK, KOFF);
    for (int off = off0; off < off1; ++off) {
        const int m  = off + (off >= CENTER_IDX ? 1 : 0);
        const int k  = m % 5;
        const int ij = m / 5;
        const int j  = ij % 21;
        const int i2 = ij / 21;
        int tz = t + k - 2;   tz = max(0, min(tz, TD - 1));
        int yz = y + i2 - 10; yz = max(0, min(yz, HD - 1));
        const int rowbase = (tz * HD + yz) * WD;
        const int xb = x0 + j - 10;

        uint2 wq = *(const uint2*)(wb + (size_t)off * NPIX + px0);
        float wv[4] = { bf2f(wq.x & 0xffffu), bf2f(wq.x >> 16),
                        bf2f(wq.y & 0xffffu), bf2f(wq.y >> 16) };
        #pragma unroll
        for (int q = 0; q < 4; ++q) {
            int xn = max(0, min(xb + q, WD - 1));
            float nb = bf2f((u32t)ob[rowbase + xn]);
            float d = c[q] - nb;
            acc = fmaf(wv[q] * d, d, acc);
        }
    }
}

// Grid: x = pixel block (32), y = offset block (64). Block = 256 threads.
__global__ __launch_bounds__(256) void bilateral_main(
    const void* __restrict__ w, const void* __restrict__ tgt,
    const void* __restrict__ outp, float* __restrict__ ws,
    const int* __restrict__ flag)
{
    __shared__ float red_s[4];
    __shared__ float red_f[4];

    const int tid = threadIdx.x;
    const int px0 = (blockIdx.x * 256 + tid) * PX_PER_LANE;
    const int f = *flag;               // wave-uniform
    float acc = 0.f, facc = 0.f;

    if (px0 < NPIX) {
        if (f) accum_bf16((const u16t*)w, (const u16t*)tgt, (const u16t*)outp,
                          px0, blockIdx.y, acc, facc);
        else   accum_f32((const float*)w, (const float*)tgt, (const float*)outp,
                         px0, blockIdx.y, acc, facc);
    }

    #pragma unroll
    for (int s = 32; s > 0; s >>= 1) {
        acc  += __shfl_down(acc, s, 64);
        facc += __shfl_down(facc, s, 64);
    }
    const int wid = tid >> 6, lane = tid & 63;
    if (lane == 0) { red_s[wid] = acc; red_f[wid] = facc; }
    __syncthreads();
    if (tid == 0) {
        atomicAdd(&ws[0], red_s[0] + red_s[1] + red_s[2] + red_s[3]);
        if (blockIdx.y == 0)
            atomicAdd(&ws[1], red_f[0] + red_f[1] + red_f[2] + red_f[3]);
    }
}

__global__ void bilateral_final(const float* __restrict__ ws,
                                const int* __restrict__ flag,
                                void* __restrict__ out)
{
    if (threadIdx.x == 0) {
        float res = (128.0f / (float)KOFF) * ws[0] + ws[1] / (float)NPIX;
        if (*flag) {                   // bf16 output, RNE
            u32t u = __float_as_uint(res);
            u32t lsb = (u >> 16) & 1u;
            u = (u + 0x7fffu + lsb) >> 16;
            ((u16t*)out)[0] = (u16t)u;
        } else {                       // f32 output
            ((float*)out)[0] = res;
        }
    }
}

extern "C" void kernel_launch(void* const* d_in, const int* in_sizes, int n_in,
                              void* d_out, int out_size, void* d_ws, size_t ws_size,
                              hipStream_t stream) {
    const void* w    = d_in[0];
    const void* tgt  = d_in[1];
    const void* outp = d_in[2];
    float* ws = (float*)d_ws;          // ws[0]=smooth, ws[1]=fidelity, ws[2]=flag
    int* flag = (int*)(ws + 2);

    (void)hipMemsetAsync(d_ws, 0, 3 * sizeof(float), stream);
    dtype_probe<<<1, 64, 0, stream>>>((const u32t*)tgt, flag);
    dim3 grid(NB_PC, NB_OFF);
    bilateral_main<<<grid, 256, 0, stream>>>(w, tgt, outp, ws, flag);
    bilateral_final<<<1, 64, 0, stream>>>(ws, flag, d_out);
}

// Round 14
// 379.491 us; speedup vs baseline: 1.0777x; 1.0389x over previous
//
#include <hip/hip_runtime.h>

#define TD 5
#define HD 80
#define WD 80
#define NPIX 32000           // 5*80*80
#define KOFF 2204            // 5*21*21 - 1
#define CENTER_IDX 1102      // (10*21+10)*5 + 2
#define PX_PER_LANE 4
#define NB_PC 32             // 8192 threads cover 8000 pixel-chunks
#define NB_OFF 64
#define OFF_CHUNK 35         // 64*35 = 2240 >= 2204
// replicate-padded volume: P[9][100][100] f32, in d_ws
#define PT 9
#define PH 100
#define PW 100
#define PVOL 90000
#define PSLICE 10000         // PH*PW
#define WS_PAD_OFF 256       // float offset of P within ws (1 KB, keeps alignment)

typedef unsigned short u16t;
typedef unsigned int u32t;
typedef float f32x4 __attribute__((ext_vector_type(4)));              // 16B-aligned
typedef float f32x4u __attribute__((ext_vector_type(4), aligned(4))); // 4B-aligned vec load

__device__ __forceinline__ float bf2f(u32t u) {
    union { u32t i; float f; } v; v.i = u << 16; return v.f;
}

// ---------- dtype probe: flag=1 if tensors are bf16, 0 if float32 ----------
__global__ void dtype_probe(const u32t* __restrict__ t, int* __restrict__ flag)
{
    int lane = threadIdx.x;            // 64 threads
    u32t v = t[lane];
    int b1 = (v >> 8) & 0xFF;
    int b3 = (v >> 24) & 0xFF;
    bool bfp = (b1 >= 0x38 && b1 < 0x40) && (b3 >= 0x38 && b3 < 0x40);
    unsigned long long m = __ballot(bfp);
    if (lane == 0) *flag = (__popcll(m) >= 32) ? 1 : 0;
}

// ---------- build replicate-padded f32 volume from output (either dtype) ----------
__global__ __launch_bounds__(256) void pad_volume(const void* __restrict__ outp,
                                                  float* __restrict__ P,
                                                  const int* __restrict__ flag)
{
    int idx = blockIdx.x * 256 + threadIdx.x;
    if (idx >= PVOL) return;
    int xx = idx % PW;
    int rem = idx / PW;
    int yy = rem % PH;
    int tt = rem / PH;
    int x = max(0, min(xx - 10, WD - 1));
    int y = max(0, min(yy - 10, HD - 1));
    int t = max(0, min(tt - 2, TD - 1));
    int src = (t * HD + y) * WD + x;
    float v = (*flag) ? bf2f((u32t)((const u16t*)outp)[src])
                      : ((const float*)outp)[src];
    P[idx] = v;
}

// ---------- f32 path: 4 consecutive px/lane, clamp-free padded gathers ----------
__device__ __forceinline__ void accum_f32(const float* __restrict__ wf,
                                          const float* __restrict__ tf,
                                          const float* __restrict__ of,
                                          const float* __restrict__ P,
                                          int px0, int by,
                                          float& acc, float& facc)
{
    const int x0 = px0 % WD;
    const int rowc = px0 / WD;         // t*80 + y
    const int y = rowc % HD;
    const int t = rowc / HD;

    const float4 c = *(const float4*)(of + px0);

    if (by == 0) {                     // fidelity, once per pixel
        float4 tv = *(const float4*)(tf + px0);
        float d0 = c.x - tv.x, d1 = c.y - tv.y, d2 = c.z - tv.z, d3 = c.w - tv.w;
        facc += d0*d0 + d1*d1 + d2*d2 + d3*d3;
    }

    const int lanebase = t * PSLICE + y * PW + x0;   // per-lane, hoisted
    const int off0 = by * OFF_CHUNK;
    const int off1 = min(off0 + OFF_CHUNK, KOFF);
    for (int off = off0; off < off1; ++off) {
        // offset enumeration m=(i*21+j)*5+k, center skipped — wave-uniform (scalar unit)
        const int m  = off + (off >= CENTER_IDX ? 1 : 0);
        const int k  = m % 5;
        const int ij = m / 5;
        const int j  = ij % 21;
        const int i2 = ij / 21;
        const int du = k * PSLICE + i2 * PW + j;     // uniform delta, no clamps

        const f32x4u nb = *(const f32x4u*)(P + lanebase + du);
        const f32x4 wv = __builtin_nontemporal_load(
            (const f32x4*)(wf + (size_t)off * NPIX + px0));

        float d0 = c.x - nb[0], d1 = c.y - nb[1], d2 = c.z - nb[2], d3 = c.w - nb[3];
        acc = fmaf(wv[0] * d0, d0, acc);
        acc = fmaf(wv[1] * d1, d1, acc);
        acc = fmaf(wv[2] * d2, d2, acc);
        acc = fmaf(wv[3] * d3, d3, acc);
    }
}

// ---------- bf16 path: same geometry, w/tgt/centers bf16, neighbors from P ----------
__device__ __forceinline__ void accum_bf16(const u16t* __restrict__ wb,
                                           const u16t* __restrict__ tb,
                                           const u16t* __restrict__ ob,
                                           const float* __restrict__ P,
                                           int px0, int by,
                                           float& acc, float& facc)
{
    const int x0 = px0 % WD;
    const int rowc = px0 / WD;
    const int y = rowc % HD;
    const int t = rowc / HD;

    float c[4];
    {
        uint2 cv = *(const uint2*)(ob + px0);
        c[0] = bf2f(cv.x & 0xffffu); c[1] = bf2f(cv.x >> 16);
        c[2] = bf2f(cv.y & 0xffffu); c[3] = bf2f(cv.y >> 16);
    }
    if (by == 0) {
        uint2 tv = *(const uint2*)(tb + px0);
        float t0 = bf2f(tv.x & 0xffffu), t1 = bf2f(tv.x >> 16);
        float t2 = bf2f(tv.y & 0xffffu), t3 = bf2f(tv.y >> 16);
        float d0 = c[0]-t0, d1 = c[1]-t1, d2 = c[2]-t2, d3 = c[3]-t3;
        facc += d0*d0 + d1*d1 + d2*d2 + d3*d3;
    }

    const int lanebase = t * PSLICE + y * PW + x0;
    const int off0 = by * OFF_CHUNK;
    const int off1 = min(off0 + OFF_CHUNK, KOFF);
    for (int off = off0; off < off1; ++off) {
        const int m  = off + (off >= CENTER_IDX ? 1 : 0);
        const int k  = m % 5;
        const int ij = m / 5;
        const int j  = ij % 21;
        const int i2 = ij / 21;
        const int du = k * PSLICE + i2 * PW + j;

        const f32x4u nb = *(const f32x4u*)(P + lanebase + du);
        uint2 wq = *(const uint2*)(wb + (size_t)off * NPIX + px0);
        float wv[4] = { bf2f(wq.x & 0xffffu), bf2f(wq.x >> 16),
                        bf2f(wq.y & 0xffffu), bf2f(wq.y >> 16) };
        #pragma unroll
        for (int q = 0; q < 4; ++q) {
            float d = c[q] - nb[q];
            acc = fmaf(wv[q] * d, d, acc);
        }
    }
}

// Grid: x = pixel block (32), y = offset block (64). Block = 256 threads.
__global__ __launch_bounds__(256) void bilateral_main(
    const void* __restrict__ w, const void* __restrict__ tgt,
    const void* __restrict__ outp, float* __restrict__ ws,
    const float* __restrict__ P, const int* __restrict__ flag)
{
    __shared__ float red_s[4];
    __shared__ float red_f[4];

    const int tid = threadIdx.x;
    const int px0 = (blockIdx.x * 256 + tid) * PX_PER_LANE;
    const int f = *flag;               // wave-uniform
    float acc = 0.f, facc = 0.f;

    if (px0 < NPIX) {
        if (f) accum_bf16((const u16t*)w, (const u16t*)tgt, (const u16t*)outp,
                          P, px0, blockIdx.y, acc, facc);
        else   accum_f32((const float*)w, (const float*)tgt, (const float*)outp,
                         P, px0, blockIdx.y, acc, facc);
    }

    #pragma unroll
    for (int s = 32; s > 0; s >>= 1) {
        acc  += __shfl_down(acc, s, 64);
        facc += __shfl_down(facc, s, 64);
    }
    const int wid = tid >> 6, lane = tid & 63;
    if (lane == 0) { red_s[wid] = acc; red_f[wid] = facc; }
    __syncthreads();
    if (tid == 0) {
        atomicAdd(&ws[0], red_s[0] + red_s[1] + red_s[2] + red_s[3]);
        if (blockIdx.y == 0)
            atomicAdd(&ws[1], red_f[0] + red_f[1] + red_f[2] + red_f[3]);
    }
}

__global__ void bilateral_final(const float* __restrict__ ws,
                                const int* __restrict__ flag,
                                void* __restrict__ out)
{
    if (threadIdx.x == 0) {
        float res = (128.0f / (float)KOFF) * ws[0] + ws[1] / (float)NPIX;
        if (*flag) {                   // bf16 output, RNE
            u32t u = __float_as_uint(res);
            u32t lsb = (u >> 16) & 1u;
            u = (u + 0x7fffu + lsb) >> 16;
            ((u16t*)out)[0] = (u16t)u;
        } else {                       // f32 output
            ((float*)out)[0] = res;
        }
    }
}

extern "C" void kernel_launch(void* const* d_in, const int* in_sizes, int n_in,
                              void* d_out, int out_size, void* d_ws, size_t ws_size,
                              hipStream_t stream) {
    const void* w    = d_in[0];
    const void* tgt  = d_in[1];
    const void* outp = d_in[2];
    float* ws = (float*)d_ws;          // ws[0]=smooth, ws[1]=fidelity, ws[2]=flag, P at +WS_PAD_OFF
    int* flag = (int*)(ws + 2);
    float* P = ws + WS_PAD_OFF;

    (void)hipMemsetAsync(d_ws, 0, 3 * sizeof(float), stream);
    dtype_probe<<<1, 64, 0, stream>>>((const u32t*)tgt, flag);
    pad_volume<<<(PVOL + 255) / 256, 256, 0, stream>>>(outp, P, flag);
    dim3 grid(NB_PC, NB_OFF);
    bilateral_main<<<grid, 256, 0, stream>>>(w, tgt, outp, ws, P, flag);
    bilateral_final<<<1, 64, 0, stream>>>(ws, flag, d_out);
}